// Round 1
// baseline (409.898 us; speedup 1.0000x reference)
//
#include <hip/hip_runtime.h>

#define BATCH 4096
#define ISZ   512
#define MT    8
#define NH    4
#define KS    8
#define NFEAT (NH * ISZ * KS)   // 16384
#define LN_EPS 1e-5f

// Fold poly_weights into kernels and transpose to [h][i][k][m] so that the 8
// m-coefficients for feature f=(h*4096+i*8+k) sit at W2[f*8 .. f*8+7].
__global__ void prep_w2(const float* __restrict__ kern, const float* __restrict__ poly,
                        float* __restrict__ W2) {
    int e = blockIdx.x * 256 + threadIdx.x;   // 0 .. 131071
    int m = e & 7;
    int f = e >> 3;                            // feature id = h*4096 + i*8 + k
    // kernels layout [h][i][m][k]: ((h*512+i)*8+m)*8+k = (f>>3)*64 + m*8 + (f&7)
    W2[e] = kern[(f >> 3) * 64 + m * 8 + (f & 7)] * poly[f];
}

template <bool USE_W2>
__global__ __launch_bounds__(512)
void cheb_main(const float* __restrict__ x, const float* __restrict__ scale,
               const float* __restrict__ W2, const float* __restrict__ kern,
               const float* __restrict__ poly,
               const float* __restrict__ gamma, const float* __restrict__ beta,
               float* __restrict__ out) {
    __shared__ float cheb[2][ISZ][MT];   // 32 KB: T0..T7 per (row, i)
    __shared__ float red[8][4];          // per-wave partials

    const int t  = threadIdx.x;
    const int r0 = blockIdx.x * 2;       // this block handles rows r0, r0+1

    // Stage Chebyshev basis for both rows. Coalesced x reads; each thread does 2 (r,i).
    for (int idx = t; idx < 2 * ISZ; idx += 512) {
        int r = idx >> 9, i = idx & 511;
        float xs = x[(r0 + r) * ISZ + i] * scale[i];
        float T0 = 1.f, T1 = xs;
        float* c = cheb[r][i];
        c[0] = T0; c[1] = T1;
        #pragma unroll
        for (int m = 2; m < MT; ++m) {
            float Tn = 2.f * xs * T1 - T0;
            c[m] = Tn; T0 = T1; T1 = Tn;
        }
    }
    __syncthreads();

    float val[2][32];                    // 64 VGPRs of silu'd features
    float sum0 = 0.f, sq0 = 0.f, sum1 = 0.f, sq1 = 0.f;

    #pragma unroll
    for (int j = 0; j < 32; ++j) {
        const int f = j * 512 + t;            // feature index, lane-adjacent
        const int i = (f >> 3) & 511;
        float w[8];
        if (USE_W2) {
            const float4* Wv = (const float4*)(W2 + (size_t)f * 8);
            float4 a = Wv[0], b = Wv[1];      // 2x dwordx4, fully coalesced
            w[0]=a.x; w[1]=a.y; w[2]=a.z; w[3]=a.w;
            w[4]=b.x; w[5]=b.y; w[6]=b.z; w[7]=b.w;
        } else {
            const float p = poly[f];
            const int base = (f >> 3) * 64 + (f & 7);
            #pragma unroll
            for (int m = 0; m < 8; ++m) w[m] = kern[base + m * 8] * p;
        }
        #pragma unroll
        for (int r = 0; r < 2; ++r) {         // weights amortized over 2 rows
            const float4* cv = (const float4*)cheb[r][i];
            float4 c0 = cv[0], c1 = cv[1];    // ds_read_b128 x2, broadcast in 8-lane groups
            float d = c0.x*w[0] + c0.y*w[1] + c0.z*w[2] + c0.w*w[3]
                    + c1.x*w[4] + c1.y*w[5] + c1.z*w[6] + c1.w*w[7];
            float s = d / (1.f + __expf(-d)); // silu; saturates correctly at +/-inf
            val[r][j] = s;
            if (r == 0) { sum0 += s; sq0 += s * s; }
            else        { sum1 += s; sq1 += s * s; }
        }
    }

    // Wave-level butterfly reduction (64 lanes)
    #pragma unroll
    for (int off = 32; off > 0; off >>= 1) {
        sum0 += __shfl_xor(sum0, off, 64);
        sq0  += __shfl_xor(sq0,  off, 64);
        sum1 += __shfl_xor(sum1, off, 64);
        sq1  += __shfl_xor(sq1,  off, 64);
    }
    const int wave = t >> 6;
    if ((t & 63) == 0) {
        red[wave][0] = sum0; red[wave][1] = sq0;
        red[wave][2] = sum1; red[wave][3] = sq1;
    }
    __syncthreads();

    float ts0 = 0.f, tq0 = 0.f, ts1 = 0.f, tq1 = 0.f;
    #pragma unroll
    for (int wv = 0; wv < 8; ++wv) {          // redundant per-thread combine (broadcast reads)
        ts0 += red[wv][0]; tq0 += red[wv][1];
        ts1 += red[wv][2]; tq1 += red[wv][3];
    }
    const float invN = 1.f / (float)NFEAT;
    const float mean0 = ts0 * invN, mean1 = ts1 * invN;
    const float var0 = fmaxf(tq0 * invN - mean0 * mean0, 0.f);
    const float var1 = fmaxf(tq1 * invN - mean1 * mean1, 0.f);
    const float rs0 = rsqrtf(var0 + LN_EPS);
    const float rs1 = rsqrtf(var1 + LN_EPS);

    float* o0 = out + (size_t)r0 * NFEAT;
    float* o1 = o0 + NFEAT;
    #pragma unroll
    for (int j = 0; j < 32; ++j) {
        const int f = j * 512 + t;
        float g = gamma[f], bb = beta[f];
        o0[f] = (val[0][j] - mean0) * rs0 * g + bb;  // coalesced dword stores
        o1[f] = (val[1][j] - mean1) * rs1 * g + bb;
    }
}

extern "C" void kernel_launch(void* const* d_in, const int* in_sizes, int n_in,
                              void* d_out, int out_size, void* d_ws, size_t ws_size,
                              hipStream_t stream) {
    const float* x     = (const float*)d_in[0];
    const float* scale = (const float*)d_in[1];
    const float* poly  = (const float*)d_in[2];
    const float* kern  = (const float*)d_in[3];
    const float* gamma = (const float*)d_in[4];
    const float* beta  = (const float*)d_in[5];
    float* out = (float*)d_out;

    const size_t W2_BYTES = (size_t)NFEAT * 8 * sizeof(float);  // 512 KB
    if (ws_size >= W2_BYTES) {
        float* W2 = (float*)d_ws;
        prep_w2<<<(NFEAT * 8) / 256, 256, 0, stream>>>(kern, poly, W2);
        cheb_main<true><<<BATCH / 2, 512, 0, stream>>>(x, scale, W2, kern, poly,
                                                       gamma, beta, out);
    } else {
        cheb_main<false><<<BATCH / 2, 512, 0, stream>>>(x, scale, nullptr, kern, poly,
                                                        gamma, beta, out);
    }
}

// Round 4
// 388.018 us; speedup vs baseline: 1.0564x; 1.0564x over previous
//
#include <hip/hip_runtime.h>

#define BATCH 4096
#define ISZ   512
#define MT    8
#define NH    4
#define KS    8
#define NFEAT (NH * ISZ * KS)   // 16384
#define LN_EPS 1e-5f

typedef float vfloat4 __attribute__((ext_vector_type(4)));  // native vector for nontemporal builtins

// Folded + swizzled weight table.
// Feature f = j*2048 + t*4 + c (j:0..7, t:0..511, c:0..3) needs coeffs m=0..7.
// Stored as float4 groups: group q = 2c + (m>>2), element l = m&3,
// at float index ((j*8+q)*512 + t)*4 + l  -> float4 id (j*8+q)*512 + t.
// This makes every weight load a lane-contiguous global_load_dwordx4.
__global__ void prep_w2(const float* __restrict__ kern, const float* __restrict__ poly,
                        float* __restrict__ W2) {
    int dst = blockIdx.x * 256 + threadIdx.x;   // 0 .. 131071
    int l = dst & 3;
    int t = (dst >> 2) & 511;
    int q = (dst >> 11) & 7;
    int j = dst >> 14;
    int c = q >> 1;
    int m = (q & 1) * 4 + l;
    int f = j * 2048 + t * 4 + c;               // feature id = h*4096 + i*8 + k
    // kernels layout [h][i][m][k]: ((h*512+i)*8+m)*8+k = (f>>3)*64 + m*8 + (f&7)
    W2[dst] = kern[(f >> 3) * 64 + m * 8 + (f & 7)] * poly[f];
}

__device__ __forceinline__ float dot8(float4 w0, float4 w1, float4 a0, float4 a1) {
    return w0.x*a0.x + w0.y*a0.y + w0.z*a0.z + w0.w*a0.w
         + w1.x*a1.x + w1.y*a1.y + w1.z*a1.z + w1.w*a1.w;
}

template <bool USE_W2>
__global__ __launch_bounds__(512)
void cheb_main(const float* __restrict__ x, const float* __restrict__ scale,
               const float4* __restrict__ W2v, const float* __restrict__ kern,
               const float* __restrict__ poly,
               const float* __restrict__ gamma, const float* __restrict__ beta,
               float* __restrict__ out) {
    __shared__ float cheb[2][ISZ][MT];   // 32 KB: T0..T7 per (row, i)
    __shared__ float red[8][4];

    const int t  = threadIdx.x;
    const int r0 = blockIdx.x * 2;

    // Stage Chebyshev basis for both rows (coalesced x reads).
    for (int idx = t; idx < 2 * ISZ; idx += 512) {
        int r = idx >> 9, i = idx & 511;
        float xs = x[(r0 + r) * ISZ + i] * scale[i];
        float T0 = 1.f, T1 = xs;
        float* c = cheb[r][i];
        c[0] = T0; c[1] = T1;
        #pragma unroll
        for (int m = 2; m < MT; ++m) {
            float Tn = 2.f * xs * T1 - T0;
            c[m] = Tn; T0 = T1; T1 = Tn;
        }
    }
    __syncthreads();

    // ---- Pass A: accumulate LN statistics (values NOT kept in registers) ----
    float sum0 = 0.f, sq0 = 0.f, sum1 = 0.f, sq1 = 0.f;
    #pragma unroll
    for (int j = 0; j < 8; ++j) {
        // input-feature index of this thread's 4 features: ((f>>3) & 511)
        const int i = (j * 256 + (t >> 1)) & 511;
        float4 wa[8];
        if (USE_W2) {
            #pragma unroll
            for (int q = 0; q < 8; ++q) wa[q] = W2v[(j * 8 + q) * 512 + t];
        } else {
            #pragma unroll
            for (int c = 0; c < 4; ++c) {
                const int f = j * 2048 + t * 4 + c;
                const float p = poly[f];
                const int base = (f >> 3) * 64 + (f & 7);
                wa[2*c]   = make_float4(kern[base]*p,      kern[base+8]*p,
                                        kern[base+16]*p,   kern[base+24]*p);
                wa[2*c+1] = make_float4(kern[base+32]*p,   kern[base+40]*p,
                                        kern[base+48]*p,   kern[base+56]*p);
            }
        }
        const float4* cv0 = (const float4*)cheb[0][i];
        const float4* cv1 = (const float4*)cheb[1][i];
        float4 a0 = cv0[0], a1 = cv0[1];
        float4 b0 = cv1[0], b1 = cv1[1];
        #pragma unroll
        for (int c = 0; c < 4; ++c) {
            float d0 = dot8(wa[2*c], wa[2*c+1], a0, a1);
            float d1 = dot8(wa[2*c], wa[2*c+1], b0, b1);
            float s0 = d0 / (1.f + __expf(-d0));
            float s1 = d1 / (1.f + __expf(-d1));
            sum0 += s0; sq0 += s0 * s0;
            sum1 += s1; sq1 += s1 * s1;
        }
    }

    // Wave butterfly + cross-wave combine
    #pragma unroll
    for (int off = 32; off > 0; off >>= 1) {
        sum0 += __shfl_xor(sum0, off, 64);
        sq0  += __shfl_xor(sq0,  off, 64);
        sum1 += __shfl_xor(sum1, off, 64);
        sq1  += __shfl_xor(sq1,  off, 64);
    }
    const int wave = t >> 6;
    if ((t & 63) == 0) {
        red[wave][0] = sum0; red[wave][1] = sq0;
        red[wave][2] = sum1; red[wave][3] = sq1;
    }
    __syncthreads();

    float ts0 = 0.f, tq0 = 0.f, ts1 = 0.f, tq1 = 0.f;
    #pragma unroll
    for (int wv = 0; wv < 8; ++wv) {
        ts0 += red[wv][0]; tq0 += red[wv][1];
        ts1 += red[wv][2]; tq1 += red[wv][3];
    }
    const float invN = 1.f / (float)NFEAT;
    const float mean0 = ts0 * invN, mean1 = ts1 * invN;
    const float rs0 = rsqrtf(fmaxf(tq0 * invN - mean0 * mean0, 0.f) + LN_EPS);
    const float rs1 = rsqrtf(fmaxf(tq1 * invN - mean1 * mean1, 0.f) + LN_EPS);

    // ---- Pass B: recompute, normalize, float4 nontemporal stores ----
    float* o0 = out + (size_t)r0 * NFEAT;
    float* o1 = o0 + NFEAT;
    #pragma unroll
    for (int j = 0; j < 8; ++j) {
        const int i  = (j * 256 + (t >> 1)) & 511;
        const int f0 = j * 2048 + t * 4;
        float4 wa[8];
        if (USE_W2) {
            #pragma unroll
            for (int q = 0; q < 8; ++q) wa[q] = W2v[(j * 8 + q) * 512 + t];
        } else {
            #pragma unroll
            for (int c = 0; c < 4; ++c) {
                const int f = f0 + c;
                const float p = poly[f];
                const int base = (f >> 3) * 64 + (f & 7);
                wa[2*c]   = make_float4(kern[base]*p,      kern[base+8]*p,
                                        kern[base+16]*p,   kern[base+24]*p);
                wa[2*c+1] = make_float4(kern[base+32]*p,   kern[base+40]*p,
                                        kern[base+48]*p,   kern[base+56]*p);
            }
        }
        const float4* cv0 = (const float4*)cheb[0][i];
        const float4* cv1 = (const float4*)cheb[1][i];
        float4 a0 = cv0[0], a1 = cv0[1];
        float4 b0 = cv1[0], b1 = cv1[1];
        float4 g  = *(const float4*)(gamma + f0);
        float4 bb = *(const float4*)(beta  + f0);
        vfloat4 r0v, r1v;
        {
            float d, s;
            d = dot8(wa[0], wa[1], a0, a1); s = d / (1.f + __expf(-d));
            r0v.x = (s - mean0) * rs0 * g.x + bb.x;
            d = dot8(wa[2], wa[3], a0, a1); s = d / (1.f + __expf(-d));
            r0v.y = (s - mean0) * rs0 * g.y + bb.y;
            d = dot8(wa[4], wa[5], a0, a1); s = d / (1.f + __expf(-d));
            r0v.z = (s - mean0) * rs0 * g.z + bb.z;
            d = dot8(wa[6], wa[7], a0, a1); s = d / (1.f + __expf(-d));
            r0v.w = (s - mean0) * rs0 * g.w + bb.w;

            d = dot8(wa[0], wa[1], b0, b1); s = d / (1.f + __expf(-d));
            r1v.x = (s - mean1) * rs1 * g.x + bb.x;
            d = dot8(wa[2], wa[3], b0, b1); s = d / (1.f + __expf(-d));
            r1v.y = (s - mean1) * rs1 * g.y + bb.y;
            d = dot8(wa[4], wa[5], b0, b1); s = d / (1.f + __expf(-d));
            r1v.z = (s - mean1) * rs1 * g.z + bb.z;
            d = dot8(wa[6], wa[7], b0, b1); s = d / (1.f + __expf(-d));
            r1v.w = (s - mean1) * rs1 * g.w + bb.w;
        }
        __builtin_nontemporal_store(r0v, (vfloat4*)(o0 + f0));
        __builtin_nontemporal_store(r1v, (vfloat4*)(o1 + f0));
    }
}

extern "C" void kernel_launch(void* const* d_in, const int* in_sizes, int n_in,
                              void* d_out, int out_size, void* d_ws, size_t ws_size,
                              hipStream_t stream) {
    const float* x     = (const float*)d_in[0];
    const float* scale = (const float*)d_in[1];
    const float* poly  = (const float*)d_in[2];
    const float* kern  = (const float*)d_in[3];
    const float* gamma = (const float*)d_in[4];
    const float* beta  = (const float*)d_in[5];
    float* out = (float*)d_out;

    const size_t W2_BYTES = (size_t)NFEAT * 8 * sizeof(float);  // 512 KB
    if (ws_size >= W2_BYTES) {
        float* W2 = (float*)d_ws;
        prep_w2<<<(NFEAT * 8) / 256, 256, 0, stream>>>(kern, poly, W2);
        cheb_main<true><<<BATCH / 2, 512, 0, stream>>>(x, scale, (const float4*)W2,
                                                       kern, poly, gamma, beta, out);
    } else {
        cheb_main<false><<<BATCH / 2, 512, 0, stream>>>(x, scale, nullptr,
                                                        kern, poly, gamma, beta, out);
    }
}

// Round 5
// 355.703 us; speedup vs baseline: 1.1524x; 1.0908x over previous
//
#include <hip/hip_runtime.h>

#define BATCH 4096
#define ISZ   512
#define MT    8
#define NH    4
#define KS    8
#define NFEAT (NH * ISZ * KS)   // 16384
#define LN_EPS 1e-5f

typedef float vfloat4 __attribute__((ext_vector_type(4)));

// Folded + swizzled weight table (unchanged from R4 — verified correct).
// Feature f = j*2048 + t*4 + c needs coeffs m=0..7, stored so that
// wa[q] = W2v[(j*8+q)*512 + t] is a lane-contiguous global_load_dwordx4.
__global__ void prep_w2(const float* __restrict__ kern, const float* __restrict__ poly,
                        float* __restrict__ W2) {
    int dst = blockIdx.x * 256 + threadIdx.x;   // 0 .. 131071
    int l = dst & 3;
    int t = (dst >> 2) & 511;
    int q = (dst >> 11) & 7;
    int j = dst >> 14;
    int c = q >> 1;
    int m = (q & 1) * 4 + l;
    int f = j * 2048 + t * 4 + c;
    // kernels layout [h][i][m][k]: (f>>3)*64 + m*8 + (f&7)
    W2[dst] = kern[(f >> 3) * 64 + m * 8 + (f & 7)] * poly[f];
}

__device__ __forceinline__ float dot8(float4 w0, float4 w1, float4 a0, float4 a1) {
    return w0.x*a0.x + w0.y*a0.y + w0.z*a0.z + w0.w*a0.w
         + w1.x*a1.x + w1.y*a1.y + w1.z*a1.z + w1.w*a1.w;
}

__device__ __forceinline__ float fast_silu(float d) {
    // 4 VALU: exp, add, rcp, mul. rcp(inf)=0 gives correct saturation.
    return d * __builtin_amdgcn_rcpf(1.f + __expf(-d));
}

// Rebuild T0..T7 from xs: 6 FMAs + 1 add.
__device__ __forceinline__ void cheb_basis(float xs, float4& a0, float4& a1) {
    float t2x = xs + xs;
    a0.x = 1.f;
    a0.y = xs;
    a0.z = t2x * a0.y - a0.x;
    a0.w = t2x * a0.z - a0.y;
    a1.x = t2x * a0.w - a0.z;
    a1.y = t2x * a1.x - a0.w;
    a1.z = t2x * a1.y - a1.x;
    a1.w = t2x * a1.z - a1.y;
}

template <bool USE_W2>
__global__ __launch_bounds__(512)
void cheb_main(const float* __restrict__ x, const float* __restrict__ scale,
               const float4* __restrict__ W2v, const float* __restrict__ kern,
               const float* __restrict__ poly,
               const float* __restrict__ gamma, const float* __restrict__ beta,
               float* __restrict__ out) {
    __shared__ float xs[2][ISZ];         // 4 KB — scaled inputs only
    __shared__ float red[8][4];

    const int t  = threadIdx.x;
    const int r0 = blockIdx.x * 2;

    // Stage xs for both rows (coalesced x reads).
    for (int idx = t; idx < 2 * ISZ; idx += 512) {
        int r = idx >> 9, i = idx & 511;
        xs[r][i] = x[(r0 + r) * ISZ + i] * scale[i];
    }
    __syncthreads();

    // ---- Pass A: LN statistics ----
    float sum0 = 0.f, sq0 = 0.f, sum1 = 0.f, sq1 = 0.f;
    #pragma unroll
    for (int j = 0; j < 8; ++j) {
        const int i = (j * 256 + (t >> 1)) & 511;   // this thread's input feature
        float4 wa[8];
        if (USE_W2) {
            #pragma unroll
            for (int q = 0; q < 8; ++q) wa[q] = W2v[(j * 8 + q) * 512 + t];
        } else {
            #pragma unroll
            for (int c = 0; c < 4; ++c) {
                const int f = j * 2048 + t * 4 + c;
                const float p = poly[f];
                const int base = (f >> 3) * 64 + (f & 7);
                wa[2*c]   = make_float4(kern[base]*p,    kern[base+8]*p,
                                        kern[base+16]*p, kern[base+24]*p);
                wa[2*c+1] = make_float4(kern[base+32]*p, kern[base+40]*p,
                                        kern[base+48]*p, kern[base+56]*p);
            }
        }
        // broadcast LDS reads (lane pairs share address; pairs span all banks)
        float xa = xs[0][i], xb = xs[1][i];
        float4 a0, a1, b0, b1;
        cheb_basis(xa, a0, a1);
        cheb_basis(xb, b0, b1);
        #pragma unroll
        for (int c = 0; c < 4; ++c) {
            float s0 = fast_silu(dot8(wa[2*c], wa[2*c+1], a0, a1));
            float s1 = fast_silu(dot8(wa[2*c], wa[2*c+1], b0, b1));
            sum0 += s0; sq0 += s0 * s0;
            sum1 += s1; sq1 += s1 * s1;
        }
    }

    // Wave butterfly + cross-wave combine
    #pragma unroll
    for (int off = 32; off > 0; off >>= 1) {
        sum0 += __shfl_xor(sum0, off, 64);
        sq0  += __shfl_xor(sq0,  off, 64);
        sum1 += __shfl_xor(sum1, off, 64);
        sq1  += __shfl_xor(sq1,  off, 64);
    }
    const int wave = t >> 6;
    if ((t & 63) == 0) {
        red[wave][0] = sum0; red[wave][1] = sq0;
        red[wave][2] = sum1; red[wave][3] = sq1;
    }
    __syncthreads();

    float ts0 = 0.f, tq0 = 0.f, ts1 = 0.f, tq1 = 0.f;
    #pragma unroll
    for (int wv = 0; wv < 8; ++wv) {
        ts0 += red[wv][0]; tq0 += red[wv][1];
        ts1 += red[wv][2]; tq1 += red[wv][3];
    }
    const float invN = 1.f / (float)NFEAT;
    const float mean0 = ts0 * invN, mean1 = ts1 * invN;
    const float rs0 = rsqrtf(fmaxf(tq0 * invN - mean0 * mean0, 0.f) + LN_EPS);
    const float rs1 = rsqrtf(fmaxf(tq1 * invN - mean1 * mean1, 0.f) + LN_EPS);

    // ---- Pass B: recompute, normalize, float4 nontemporal stores ----
    float* o0 = out + (size_t)r0 * NFEAT;
    float* o1 = o0 + NFEAT;
    #pragma unroll
    for (int j = 0; j < 8; ++j) {
        const int i  = (j * 256 + (t >> 1)) & 511;
        const int f0 = j * 2048 + t * 4;
        float4 wa[8];
        if (USE_W2) {
            #pragma unroll
            for (int q = 0; q < 8; ++q) wa[q] = W2v[(j * 8 + q) * 512 + t];
        } else {
            #pragma unroll
            for (int c = 0; c < 4; ++c) {
                const int f = f0 + c;
                const float p = poly[f];
                const int base = (f >> 3) * 64 + (f & 7);
                wa[2*c]   = make_float4(kern[base]*p,    kern[base+8]*p,
                                        kern[base+16]*p, kern[base+24]*p);
                wa[2*c+1] = make_float4(kern[base+32]*p, kern[base+40]*p,
                                        kern[base+48]*p, kern[base+56]*p);
            }
        }
        float xa = xs[0][i], xb = xs[1][i];
        float4 a0, a1, b0, b1;
        cheb_basis(xa, a0, a1);
        cheb_basis(xb, b0, b1);
        float4 g  = *(const float4*)(gamma + f0);
        float4 bb = *(const float4*)(beta  + f0);
        vfloat4 r0v, r1v;
        {
            float s;
            s = fast_silu(dot8(wa[0], wa[1], a0, a1));
            r0v.x = (s - mean0) * rs0 * g.x + bb.x;
            s = fast_silu(dot8(wa[2], wa[3], a0, a1));
            r0v.y = (s - mean0) * rs0 * g.y + bb.y;
            s = fast_silu(dot8(wa[4], wa[5], a0, a1));
            r0v.z = (s - mean0) * rs0 * g.z + bb.z;
            s = fast_silu(dot8(wa[6], wa[7], a0, a1));
            r0v.w = (s - mean0) * rs0 * g.w + bb.w;

            s = fast_silu(dot8(wa[0], wa[1], b0, b1));
            r1v.x = (s - mean1) * rs1 * g.x + bb.x;
            s = fast_silu(dot8(wa[2], wa[3], b0, b1));
            r1v.y = (s - mean1) * rs1 * g.y + bb.y;
            s = fast_silu(dot8(wa[4], wa[5], b0, b1));
            r1v.z = (s - mean1) * rs1 * g.z + bb.z;
            s = fast_silu(dot8(wa[6], wa[7], b0, b1));
            r1v.w = (s - mean1) * rs1 * g.w + bb.w;
        }
        __builtin_nontemporal_store(r0v, (vfloat4*)(o0 + f0));
        __builtin_nontemporal_store(r1v, (vfloat4*)(o1 + f0));
    }
}

extern "C" void kernel_launch(void* const* d_in, const int* in_sizes, int n_in,
                              void* d_out, int out_size, void* d_ws, size_t ws_size,
                              hipStream_t stream) {
    const float* x     = (const float*)d_in[0];
    const float* scale = (const float*)d_in[1];
    const float* poly  = (const float*)d_in[2];
    const float* kern  = (const float*)d_in[3];
    const float* gamma = (const float*)d_in[4];
    const float* beta  = (const float*)d_in[5];
    float* out = (float*)d_out;

    const size_t W2_BYTES = (size_t)NFEAT * 8 * sizeof(float);  // 512 KB
    if (ws_size >= W2_BYTES) {
        float* W2 = (float*)d_ws;
        prep_w2<<<(NFEAT * 8) / 256, 256, 0, stream>>>(kern, poly, W2);
        cheb_main<true><<<BATCH / 2, 512, 0, stream>>>(x, scale, (const float4*)W2,
                                                       kern, poly, gamma, beta, out);
    } else {
        cheb_main<false><<<BATCH / 2, 512, 0, stream>>>(x, scale, nullptr,
                                                        kern, poly, gamma, beta, out);
    }
}